// Round 8
// baseline (258.892 us; speedup 1.0000x reference)
//
#include <hip/hip_runtime.h>

#define CH 30
#define CELLS 49
#define ROW 1470            // floats per batch row
#define NPAIR 735           // float2 pairs per row
#define ITS 12              // ceil(735/64) pairs per lane
#define WPB 2               // waves per block == rows per block
#define THREADS 128
#define REGION_DW 2940      // dwords per 2-row region (11760 B, 16B-aligned)
#define CHUNKS 11           // full 1024B DMA chunks per tensor region
#define TAIL_DW 124         // REGION_DW - CHUNKS*256

__device__ __forceinline__ float waveReduce(float v) {
    #pragma unroll
    for (int o = 32; o > 0; o >>= 1) v += __shfl_xor(v, o, 64);
    return v;
}

// width-16 async global->LDS DMA: lds dest = uniform base + lane*16 (m104)
__device__ __forceinline__ void dma16(const float* g, float* l) {
    __builtin_amdgcn_global_load_lds(
        (const __attribute__((address_space(1))) void*)g,
        (__attribute__((address_space(3))) void*)l, 16, 0, 0);
}

__global__ __launch_bounds__(THREADS) void yolo_main(const float* __restrict__ pred,
                                                     const float* __restrict__ targ,
                                                     float* __restrict__ ws,
                                                     int* __restrict__ cnt,
                                                     float* __restrict__ out,
                                                     int B, float invB) {
    const int w = threadIdx.x >> 6;
    const int lane = threadIdx.x & 63;
    const int NBLK = gridDim.x;
    const int r0 = blockIdx.x * WPB;
    const int r = r0 + w;

    __shared__ float spA[REGION_DW];          // 2 pred rows, contiguous
    __shared__ float stA[REGION_DW];          // 2 targ rows, contiguous
    __shared__ float4 boxS[WPB][2 * CELLS];
    __shared__ int clist[WPB][CELLS];
    __shared__ float sred[WPB][3];
    __shared__ int lastFlag;

    const size_t gbase = (size_t)r0 * ROW;    // region start (16B-aligned)

    // ---- async DMA: wave0 streams pred region, wave1 streams targ region ----
    if (r0 + WPB <= B) {
        const float* gsrc = (w == 0) ? (pred + gbase) : (targ + gbase);
        float* ldst = (w == 0) ? spA : stA;
        #pragma unroll
        for (int c = 0; c < CHUNKS; ++c)
            dma16(gsrc + c * 256 + lane * 4, ldst + c * 256);
        // tail: 124 dwords = 62 lanes x float2 (8B-aligned on both sides)
        if (lane < TAIL_DW / 2) {
            const float2 v = *(const float2*)(gsrc + CHUNKS * 256 + 2 * lane);
            *(float2*)(ldst + CHUNKS * 256 + 2 * lane) = v;
        }
    } else {
        // partial last block: plain copy of valid rows
        for (int rr = 0; rr < WPB; ++rr) {
            if (r0 + rr >= B) break;
            const float2* ps = (const float2*)(pred + (size_t)(r0 + rr) * ROW);
            const float2* ts = (const float2*)(targ + (size_t)(r0 + rr) * ROW);
            for (int j = threadIdx.x; j < NPAIR; j += THREADS) {
                *(float2*)(spA + rr * ROW + 2 * j) = ps[j];
                *(float2*)(stA + rr * ROW + 2 * j) = ts[j];
            }
        }
    }
    __syncthreads();                          // drains DMA (vmcnt) + LDS writes

    const bool rowOk = (r < B);
    const float* Prow = spA + w * ROW;        // w*5880B: 8-aligned -> float2 ok
    const float* Trow = stA + w * ROW;

    float cls = 0.f, objc = 0.f, coord = 0.f;
    unsigned long long mask = 0ull;
    int nObj = 0;

    if (rowOk) {
        // ---- obj mask from LDS conf reads (cheap; no global gather) ----
        const bool isObj = (lane < CELLS) && (Trow[lane * CH + 4] > 0.f);
        mask = __ballot(isObj);
        nObj = __popcll(mask);
        if (isObj) clist[w][__popcll(mask & ((1ull << lane) - 1ull))] = lane;

        // ---- branch-free consume of both rows from LDS ----
        const float2* P2 = (const float2*)Prow;
        const float2* T2 = (const float2*)Trow;
        #pragma unroll
        for (int it = 0; it < ITS; ++it) {
            const int j = lane + it * 64;
            const bool valid = j < NPAIR;
            const int jc = valid ? j : NPAIR - 1;
            const float2 p = P2[jc];
            const float2 t = T2[jc];
            const int cell = (j * 17477) >> 18;          // j/15 for j<=767
            const int ch0 = 2 * (j - cell * 15);
            const float wobj = (float)((mask >> cell) & 1ull);
            const float dx = p.x - t.x;
            const float dy = p.y - t.y;
            cls += (valid && ch0 >= 10) ? wobj * (dx * dx + dy * dy) : 0.f;
            const float nn = (ch0 == 4 ? dx * dx : 0.f) + (ch0 == 8 ? dy * dy : 0.f);
            objc += valid ? 0.5f * (1.f - wobj) * nn : 0.f;
        }

        const int nBox = 2 * nObj;

        // ---- masked pred boxes -> xyxy (LDS reads) ----
        for (int e = lane; e < nBox; e += 64) {
            const int c = clist[w][e >> 1];
            const float* pb = Prow + c * CH + (e & 1) * 5;
            const float cx = pb[0], cy = pb[1], bw = pb[2], bh = pb[3];
            boxS[w][e] = make_float4(cx - 0.5f * bw, cy - 0.5f * bh,
                                     cx + 0.5f * bw, cy + 0.5f * bh);
        }

        // ---- per masked target box: max IoU; losses (all LDS) ----
        for (int e = lane; e < nBox; e += 64) {
            const int c = clist[w][e >> 1];
            const float* tb = Trow + c * CH + (e & 1) * 5;
            const float tcx = tb[0], tcy = tb[1], tw = tb[2], th = tb[3];
            const float tx1 = tcx - 0.5f * tw, ty1 = tcy - 0.5f * th;
            const float tx2 = tcx + 0.5f * tw, ty2 = tcy + 0.5f * th;
            const float ta = (tx2 - tx1) * (ty2 - ty1);
            float maxiou = 0.f;
            for (int i = 0; i < nBox; ++i) {
                const float4 pb4 = boxS[w][i];          // broadcast
                const float lx = fmaxf(pb4.x, tx1), ly = fmaxf(pb4.y, ty1);
                const float rx = fminf(pb4.z, tx2), ry = fminf(pb4.w, ty2);
                const float iw = fmaxf(rx - lx, 0.f), ih = fmaxf(ry - ly, 0.f);
                const float inter = iw * ih;
                const float pa = (pb4.z - pb4.x) * (pb4.w - pb4.y);
                const float un = pa + ta - inter;
                const float iou = inter / (un > 0.f ? un : 1.f);
                maxiou = fmaxf(maxiou, iou);
            }
            if (maxiou != 0.f) {                        // cmask
                const float* pb = Prow + c * CH + (e & 1) * 5;
                const float dcx = pb[0] - tcx, dcy = pb[1] - tcy;
                coord += dcx * dcx + dcy * dcy;
                const float dw = sqrtf(pb[2]) - sqrtf(tw);
                const float dh = sqrtf(pb[3]) - sqrtf(th);
                coord += dw * dw + dh * dh;
                const float dc = pb[4] - tb[4];
                objc += dc * dc;
            }
        }
    }

    // ---- wave reduce -> block triple -> arrival counter ----
    cls = waveReduce(cls); objc = waveReduce(objc); coord = waveReduce(coord);
    if (lane == 0) { sred[w][0] = cls; sred[w][1] = objc; sred[w][2] = coord; }
    __syncthreads();
    if (threadIdx.x == 0) {
        float c = 0.f, o = 0.f, x = 0.f;
        #pragma unroll
        for (int i = 0; i < WPB; ++i) { c += sred[i][0]; o += sred[i][1]; x += sred[i][2]; }
        ws[blockIdx.x] = c;
        ws[NBLK + blockIdx.x] = o;
        ws[2 * NBLK + blockIdx.x] = x;
        __threadfence();
        const int old = atomicAdd(cnt, 1);
        lastFlag = (old == NBLK - 1) ? 1 : 0;
    }
    __syncthreads();

    // ---- last block finalizes ----
    if (lastFlag) {
        __threadfence();
        float c = 0.f, o = 0.f, x = 0.f;
        for (int i = threadIdx.x; i < NBLK; i += THREADS) {
            c += ws[i];
            o += ws[NBLK + i];
            x += ws[2 * NBLK + i];
        }
        c = waveReduce(c); o = waveReduce(o); x = waveReduce(x);
        if (lane == 0) { sred[w][0] = c; sred[w][1] = o; sred[w][2] = x; }
        __syncthreads();
        if (threadIdx.x == 0) {
            float C = 0.f, O = 0.f, X = 0.f;
            #pragma unroll
            for (int i = 0; i < WPB; ++i) { C += sred[i][0]; O += sred[i][1]; X += sred[i][2]; }
            const float bcls = C * invB;
            const float bobj = O * invB;               // noobj*0.5 folded upstream
            const float bcoord = X * 5.0f * invB;      // COORD_LAMBDA
            out[0] = bcls + bobj + bcoord;
            out[1] = bcls;
            out[2] = bobj;
            out[3] = bcoord;
        }
    }
}

extern "C" void kernel_launch(void* const* d_in, const int* in_sizes, int n_in,
                              void* d_out, int out_size, void* d_ws, size_t ws_size,
                              hipStream_t stream) {
    const float* pred = (const float*)d_in[0];
    const float* targ = (const float*)d_in[1];
    float* ws = (float*)d_ws;
    float* out = (float*)d_out;
    const int B = in_sizes[0] / ROW;
    const int NBLK = (B + WPB - 1) / WPB;
    int* cnt = (int*)(ws + 3 * NBLK);

    hipMemsetAsync(cnt, 0, sizeof(int), stream);
    yolo_main<<<NBLK, THREADS, 0, stream>>>(pred, targ, ws, cnt, out, B, 1.0f / (float)B);
}